// Round 6
// baseline (517.894 us; speedup 1.0000x reference)
//
#include <hip/hip_runtime.h>
#include <cstdint>
#include <cstddef>

typedef __bf16 bf16x8 __attribute__((ext_vector_type(8)));
typedef float f32x4 __attribute__((ext_vector_type(4)));
typedef float f32x16 __attribute__((ext_vector_type(16)));
typedef unsigned short u16;

namespace {
constexpr int Bb = 4, Tt = 2048, Cc = 1024, Hh = 16, Dd = 64;
constexpr int ROWS = Bb * Tt;   // 8192
constexpr int C3 = 3 * Cc;      // 3072
constexpr float LNEPS = 1e-5f;
constexpr float SCL2 = 0.18033688011112042f; // 0.125 * log2(e)
}

__device__ __forceinline__ u16 f2bf(float f) {
  union { float f; unsigned u; } v; v.f = f;
  return (u16)((v.u + 0x7fffu + ((v.u >> 16) & 1u)) >> 16);
}
__device__ __forceinline__ u16 bfn(float f) {   // native v_cvt (RNE)
  union { __bf16 b; u16 u; } t; t.b = (__bf16)f; return t.u;
}
__device__ __forceinline__ unsigned pk2(float lo, float hi) {
  union { __bf16 b[2]; unsigned u; } t;
  t.b[0] = (__bf16)lo; t.b[1] = (__bf16)hi;
  return t.u;
}
__device__ __forceinline__ float exp2_hw(float x) {  // 2^x, one v_exp_f32
  float r;
  asm("v_exp_f32 %0, %1" : "=v"(r) : "v"(x));
  return r;
}

typedef __attribute__((address_space(3))) unsigned lds_u32;
typedef __attribute__((address_space(1))) const unsigned glb_u32;
__device__ __forceinline__ void gload_lds16(const u16* g, u16* l) {
  __builtin_amdgcn_global_load_lds((glb_u32*)g, (lds_u32*)l, 16, 0, 0);
}

// ---------------- LayerNorm (fp32 in -> bf16 out) ----------------
__global__ __launch_bounds__(256) void ln_kernel(
    const float* __restrict__ x, const float* __restrict__ g,
    const float* __restrict__ b, u16* __restrict__ out)
{
  const int row = blockIdx.x;
  const int tid = threadIdx.x;
  const float4 v = reinterpret_cast<const float4*>(x + (size_t)row * Cc)[tid];
  float s  = v.x + v.y + v.z + v.w;
  float ss = v.x * v.x + v.y * v.y + v.z * v.z + v.w * v.w;
#pragma unroll
  for (int off = 32; off; off >>= 1) {
    s  += __shfl_xor(s, off);
    ss += __shfl_xor(ss, off);
  }
  __shared__ float sa[4], sb[4];
  const int w = tid >> 6;
  if ((tid & 63) == 0) { sa[w] = s; sb[w] = ss; }
  __syncthreads();
  s  = sa[0] + sa[1] + sa[2] + sa[3];
  ss = sb[0] + sb[1] + sb[2] + sb[3];
  const float mu   = s * (1.0f / Cc);
  const float var  = ss * (1.0f / Cc) - mu * mu;
  const float rstd = rsqrtf(var + LNEPS);
  const float4 gv = reinterpret_cast<const float4*>(g)[tid];
  const float4 bv = reinterpret_cast<const float4*>(b)[tid];
  ushort4 o;
  o.x = f2bf((v.x - mu) * rstd * gv.x + bv.x);
  o.y = f2bf((v.y - mu) * rstd * gv.y + bv.y);
  o.z = f2bf((v.z - mu) * rstd * gv.z + bv.z);
  o.w = f2bf((v.w - mu) * rstd * gv.w + bv.w);
  reinterpret_cast<ushort4*>(out + (size_t)row * Cc)[tid] = o;
}

// ---------------- weight transpose + cast: w[K][N] f32 -> wt[N][K] bf16 ----------------
__global__ __launch_bounds__(256) void wcast_t(
    const float* __restrict__ w, u16* __restrict__ wt, int K, int N)
{
  __shared__ float tile[32][33];
  const int n0 = blockIdx.x * 32, k0 = blockIdx.y * 32;
  const int tx = threadIdx.x & 31, ty = threadIdx.x >> 5; // 32x8
#pragma unroll
  for (int i = 0; i < 4; i++)
    tile[ty + i * 8][tx] = w[(size_t)(k0 + ty + i * 8) * N + n0 + tx];
  __syncthreads();
#pragma unroll
  for (int i = 0; i < 4; i++)
    wt[(size_t)(n0 + ty + i * 8) * K + k0 + tx] = f2bf(tile[tx][ty + i * 8]);
}

// ---------------- GEMM 256x256, 8-phase counted-vmcnt (T1+T2+T3+T4+T5) ----------------
// BK=32; 4 K-tile LDS buffers (2 pairs, 128 KB). Iter i computes pair {2i,2i+1}
// while staging pair {2i+2,2i+3} (1 half-tile = 1 gload_lds16/thread per phase).
// vmcnt(4) at phases 4 & 8 (never 0 mid-loop): 4 oldest = tile needed next.
// T2 swizzle: LDS chunk ^= row&3, applied on global SOURCE and ds_read (rule 21).
enum { EPI_BIAS_BF16 = 0, EPI_BIAS_RELU_BF16 = 1, EPI_BIAS_RES_F32 = 2 };

template <int EPI>
__global__ __launch_bounds__(512, 2) void gemm256(
    const u16* __restrict__ A, const u16* __restrict__ Bt,
    const float* __restrict__ bias, const float* __restrict__ res,
    void* __restrict__ outp, int M, int N, int K)
{
  __shared__ alignas(16) u16 Al[2][2][256 * 32];   // [pair][ct][row*32+chunk*8]
  __shared__ alignas(16) u16 Bl[2][2][256 * 32];

  const int tid  = threadIdx.x;
  const int lane = tid & 63;
  const int wv   = tid >> 6;            // 0..7 (2M x 4N)
  const int lr   = lane & 15;
  const int lg   = (lane >> 4) & 3;

  // T1: XCD-bijective swizzle (grid % 8 == 0 by construction)
  const int q8  = (int)gridDim.x >> 3;
  const int lid = ((int)blockIdx.x & 7) * q8 + ((int)blockIdx.x >> 3);
  const int bm = (lid & 31) << 8;       // M/256 == 32 fixed
  const int bn = (lid >> 5) << 8;

  // staging geometry: thread covers LDS linear chunk tid (row tid>>2, chunk tid&3)
  const int srow = tid >> 2;                 // 0..127 (within half)
  const int schk = (tid & 3) ^ (srow & 3);   // inverse-swizzled global chunk
  const u16* gA = A  + (size_t)(bm + srow) * K + schk * 8;
  const u16* gB = Bt + (size_t)(bn + srow) * K + schk * 8;

  // frag-read geometry
  const int arow = (wv >> 2) * 128 + lr;     // + mi*16
  const int brow = (wv & 3) * 64 + lr;       // + nj*16
  const int fswz = (lg ^ (lr & 3)) * 8;      // swizzled chunk (u16 offset)

  f32x4 acc[8][4];
#pragma unroll
  for (int mi = 0; mi < 8; mi++)
#pragma unroll
    for (int nj = 0; nj < 4; nj++)
      acc[mi][nj] = (f32x4){0.f, 0.f, 0.f, 0.f};

  const int NIT = K >> 6;   // pairs of BK=32 K-tiles (K=1024 -> 16, K=4096 -> 64)

  // prologue: stage K-tiles 0,1 into pair buffer 0 (8 loads), wait oldest 4
#pragma unroll
  for (int ct = 0; ct < 2; ++ct) {
#pragma unroll
    for (int ph = 0; ph < 4; ++ph) {
      const int h = ph & 1;
      if (ph < 2)
        gload_lds16(gA + (size_t)(128 * h) * K + ct * 32, &Al[0][ct][h * 4096 + tid * 8]);
      else
        gload_lds16(gB + (size_t)(128 * h) * K + ct * 32, &Bl[0][ct][h * 4096 + tid * 8]);
    }
  }
  asm volatile("s_waitcnt vmcnt(4)" ::: "memory");
  asm volatile("s_barrier" ::: "memory");

  for (int it = 0; it < NIT; ++it) {
    const int cp = it & 1;
    const bool st = (it + 1 < NIT);
#pragma unroll
    for (int ct = 0; ct < 2; ++ct) {
      const u16* Ac = &Al[cp][ct][0];
      const u16* Bc = &Bl[cp][ct][0];
      bf16x8 bfr[4];
#pragma unroll
      for (int p = 0; p < 4; ++p) {
        // ds-reads for this phase (consumed after the barrier)
        if (p == 0) {
#pragma unroll
          for (int nj = 0; nj < 4; ++nj)
            bfr[nj] = *reinterpret_cast<const bf16x8*>(Bc + (brow + nj * 16) * 32 + fswz);
        }
        bf16x8 af[2];
#pragma unroll
        for (int m2 = 0; m2 < 2; ++m2)
          af[m2] = *reinterpret_cast<const bf16x8*>(Ac + (arow + (p * 2 + m2) * 16) * 32 + fswz);
        // stage one half-tile of the next pair
        if (st) {
          const int kt = 2 * (it + 1) + ct;
          const int h = p & 1;
          if (p < 2)
            gload_lds16(gA + (size_t)(128 * h) * K + kt * 32, &Al[cp ^ 1][ct][h * 4096 + tid * 8]);
          else
            gload_lds16(gB + (size_t)(128 * h) * K + kt * 32, &Bl[cp ^ 1][ct][h * 4096 + tid * 8]);
        }
        // counted waits at phases 4 and 8 (drain only in the last iteration)
        if (p == 3) {
          if (st) asm volatile("s_waitcnt vmcnt(4)" ::: "memory");
          else if (ct == 0) asm volatile("s_waitcnt vmcnt(0)" ::: "memory");
        }
        asm volatile("s_barrier" ::: "memory");
        __builtin_amdgcn_s_setprio(1);
#pragma unroll
        for (int m2 = 0; m2 < 2; ++m2)
#pragma unroll
          for (int nj = 0; nj < 4; ++nj)
            acc[p * 2 + m2][nj] = __builtin_amdgcn_mfma_f32_16x16x32_bf16(
                af[m2], bfr[nj], acc[p * 2 + m2][nj], 0, 0, 0);
        __builtin_amdgcn_s_setprio(0);
        asm volatile("s_barrier" ::: "memory");
      }
    }
  }

  // epilogue
#pragma unroll
  for (int mi = 0; mi < 8; ++mi) {
    const int row0 = bm + (wv >> 2) * 128 + mi * 16 + lg * 4;
#pragma unroll
    for (int nj = 0; nj < 4; ++nj) {
      const int col = bn + (wv & 3) * 64 + nj * 16 + lr;
      const float bv = bias[col];
#pragma unroll
      for (int r = 0; r < 4; ++r) {
        const int row = row0 + r;
        float v = acc[mi][nj][r] + bv;
        if constexpr (EPI == EPI_BIAS_RELU_BF16) v = fmaxf(v, 0.0f);
        if constexpr (EPI == EPI_BIAS_RES_F32) {
          float* out = (float*)outp;
          out[(size_t)row * N + col] = v + res[(size_t)row * N + col];
        } else {
          ((u16*)outp)[(size_t)row * N + col] = f2bf(v);
        }
      }
    }
  }
}

// ---------------- V transpose: qkv[B][T][3C] (v part) -> vt[B][H][D][T] ----------------
__global__ __launch_bounds__(256) void build_vt(
    const u16* __restrict__ qkv, u16* __restrict__ vt)
{
  __shared__ u16 tile[64][80];
  const int t0 = blockIdx.x * 64;
  const int h  = blockIdx.y;
  const int b  = blockIdx.z;
  const int tid = threadIdx.x;
  const int rr = tid >> 3, cc = (tid & 7) * 8;
#pragma unroll
  for (int p = 0; p < 2; p++) {
    const int t = rr + p * 32;
    bf16x8 v = *reinterpret_cast<const bf16x8*>(
        &qkv[(size_t)(b * Tt + t0 + t) * C3 + 2 * Cc + h * Dd + cc]);
    *reinterpret_cast<bf16x8*>(&tile[t][cc]) = v;
  }
  __syncthreads();
#pragma unroll
  for (int p = 0; p < 2; p++) {
    const int d = rr + p * 32;
    union { u16 u[8]; int4 v; } o;
#pragma unroll
    for (int j = 0; j < 8; j++) o.u[j] = tile[cc + j][d];
    *reinterpret_cast<int4*>(&vt[(size_t)((b * Hh + h) * Dd + d) * Tt + t0 + cc]) = o.v;
  }
}

// ---------------- flash attention: 32x32 double-swapped, pair-balanced (R4) ----------------
__global__ __launch_bounds__(256, 4) void flash_attn(
    const u16* __restrict__ qkv,   // [B][T][3C]
    const u16* __restrict__ vt,    // [B][H][D][T]
    u16* __restrict__ y)           // [B][T][C]
{
  const int tid = threadIdx.x, lane = tid & 63, wv = tid >> 6;
  const int l31 = lane & 31, hf = lane >> 5;
  const bool lo = (lane < 32);

  // 512 blocks = 8 XCDs x 64; lid = bh*8 + pg (bh pinned to one XCD)
  const int bid = blockIdx.x;
  const int lid = (bid & 7) * 64 + (bid >> 3);
  const int bh = lid >> 3, pg = lid & 7;
  const int b = bh >> 4, h = bh & 15;
  const int pi = pg * 4 + wv;        // 0..31 -> tiles {pi, 63-pi}

  const u16* qbase = qkv + (size_t)b * Tt * C3 + h * Dd;
  const u16* kbase = qbase + Cc;
  const u16* vbase = vt + (size_t)bh * Dd * Tt;

#pragma unroll
  for (int ti = 0; ti < 2; ti++) {
    const int t = ti ? (63 - pi) : pi;
    const int q0 = t * 32;

    bf16x8 qf[4];
#pragma unroll
    for (int kc = 0; kc < 4; kc++)
      qf[kc] = *reinterpret_cast<const bf16x8*>(
          &qbase[(size_t)(q0 + l31) * C3 + kc * 16 + hf * 8]);

    f32x16 oacc[2];
#pragma unroll
    for (int i = 0; i < 16; i++) { oacc[0][i] = 0.f; oacc[1][i] = 0.f; }
    float mrun = -INFINITY, lpart = 0.0f;

    const u16* kptr = &kbase[(size_t)l31 * C3 + hf * 8];
    const u16* vptr0 = &vbase[(size_t)l31 * Tt + hf * 8];
    const u16* vptr1 = vptr0 + (size_t)32 * Tt;
    bf16x8 kf[4];
#pragma unroll
    for (int kc = 0; kc < 4; kc++)
      kf[kc] = *reinterpret_cast<const bf16x8*>(kptr + kc * 16);

    for (int k0 = 0; k0 <= q0; k0 += 32) {
      bf16x8 vf[2][2];
#pragma unroll
      for (int ch = 0; ch < 2; ch++) {
        vf[0][ch] = *reinterpret_cast<const bf16x8*>(vptr0 + ch * 16);
        vf[1][ch] = *reinterpret_cast<const bf16x8*>(vptr1 + ch * 16);
      }
      vptr0 += 32; vptr1 += 32;

      f32x16 sacc;
#pragma unroll
      for (int i = 0; i < 16; i++) sacc[i] = 0.f;
#pragma unroll
      for (int kc = 0; kc < 4; kc++)
        sacc = __builtin_amdgcn_mfma_f32_32x32x16_bf16(kf[kc], qf[kc], sacc, 0, 0, 0);

      kptr += (size_t)32 * C3;
      bf16x8 kn[4];
      if (k0 < q0) {
#pragma unroll
        for (int kc = 0; kc < 4; kc++)
          kn[kc] = *reinterpret_cast<const bf16x8*>(kptr + kc * 16);
      }

      float sv[16];
#pragma unroll
      for (int r = 0; r < 16; r++) sv[r] = sacc[r];
      if (k0 == q0) {   // diagonal: mask key > q (key = (r&3)+8*(r>>2)+4hf)
#pragma unroll
        for (int r = 0; r < 16; r++)
          if ((r & 3) + 8 * (r >> 2) + 4 * hf > l31) sv[r] = -INFINITY;
      }

      float ma = fmaxf(fmaxf(sv[0], sv[1]), fmaxf(sv[2], sv[3]));
      float mb = fmaxf(fmaxf(sv[4], sv[5]), fmaxf(sv[6], sv[7]));
      float mc = fmaxf(fmaxf(sv[8], sv[9]), fmaxf(sv[10], sv[11]));
      float md = fmaxf(fmaxf(sv[12], sv[13]), fmaxf(sv[14], sv[15]));
      float m8 = fmaxf(fmaxf(ma, mb), fmaxf(mc, md));
      m8 = fmaxf(m8, __shfl_xor(m8, 32));

      if (!__all(m8 - mrun <= 64.0f)) {   // defer-max: 64 raw = 8 nats
        const float mnew  = fmaxf(mrun, m8);
        const float alpha = exp2_hw((mrun - mnew) * SCL2);
        lpart *= alpha;
#pragma unroll
        for (int i = 0; i < 16; i++) { oacc[0][i] *= alpha; oacc[1][i] *= alpha; }
        mrun = mnew;
      }

      const float ms = mrun * SCL2;
      float p[16];
#pragma unroll
      for (int r = 0; r < 16; r++)
        p[r] = exp2_hw(fmaf(sv[r], SCL2, -ms));
      {
        float s0 = (p[0] + p[1]) + (p[2] + p[3]);
        float s1 = (p[4] + p[5]) + (p[6] + p[7]);
        float s2 = (p[8] + p[9]) + (p[10] + p[11]);
        float s3 = (p[12] + p[13]) + (p[14] + p[15]);
        lpart += (s0 + s1) + (s2 + s3);
      }

      unsigned pw[2][4];
#pragma unroll
      for (int ch = 0; ch < 2; ch++) {
        const int bs = ch * 8;
        unsigned w0 = pk2(p[bs + 0], p[bs + 1]);
        unsigned w2 = pk2(p[bs + 4], p[bs + 5]);
        unsigned h0 = __shfl_xor((int)w0, 32), h2 = __shfl_xor((int)w2, 32);
        pw[ch][0] = lo ? w0 : h2;
        pw[ch][2] = lo ? h0 : w2;
        unsigned w1 = pk2(p[bs + 2], p[bs + 3]);
        unsigned w3 = pk2(p[bs + 6], p[bs + 7]);
        unsigned h1 = __shfl_xor((int)w1, 32), h3 = __shfl_xor((int)w3, 32);
        pw[ch][1] = lo ? w1 : h3;
        pw[ch][3] = lo ? h1 : w3;
      }

#pragma unroll
      for (int d0i = 0; d0i < 2; d0i++)
#pragma unroll
        for (int ch = 0; ch < 2; ch++) {
          union { unsigned w[4]; bf16x8 v; } pb;
          pb.w[0] = pw[ch][0]; pb.w[1] = pw[ch][1];
          pb.w[2] = pw[ch][2]; pb.w[3] = pw[ch][3];
          oacc[d0i] = __builtin_amdgcn_mfma_f32_32x32x16_bf16(vf[d0i][ch], pb.v, oacc[d0i], 0, 0, 0);
        }

      if (k0 < q0) {
#pragma unroll
        for (int kc = 0; kc < 4; kc++) kf[kc] = kn[kc];
      }
    }

    const float ls = lpart + __shfl_xor(lpart, 32);
    const float inv = 1.0f / ls;
    u16* yrow = y + (size_t)(b * Tt + q0 + l31) * Cc + h * Dd;
#pragma unroll
    for (int d0i = 0; d0i < 2; d0i++)
#pragma unroll
      for (int qd = 0; qd < 4; qd++) {
        ushort4 o;
        o.x = bfn(oacc[d0i][qd * 4 + 0] * inv);
        o.y = bfn(oacc[d0i][qd * 4 + 1] * inv);
        o.z = bfn(oacc[d0i][qd * 4 + 2] * inv);
        o.w = bfn(oacc[d0i][qd * 4 + 3] * inv);
        *reinterpret_cast<ushort4*>(&yrow[d0i * 32 + qd * 8 + hf * 4]) = o;
      }
  }
}

// ---------------- launch ----------------
extern "C" void kernel_launch(void* const* d_in, const int* in_sizes, int n_in,
                              void* d_out, int out_size, void* d_ws, size_t ws_size,
                              hipStream_t stream)
{
  const float* x      = (const float*)d_in[0];
  const float* ln1_g  = (const float*)d_in[1];
  const float* ln1_b  = (const float*)d_in[2];
  const float* attn_w = (const float*)d_in[3];
  const float* attn_b = (const float*)d_in[4];
  const float* proj_w = (const float*)d_in[5];
  const float* proj_b = (const float*)d_in[6];
  const float* ln2_g  = (const float*)d_in[7];
  const float* ln2_b  = (const float*)d_in[8];
  const float* fc1_w  = (const float*)d_in[9];
  const float* fc1_b  = (const float*)d_in[10];
  const float* fc2_w  = (const float*)d_in[11];
  const float* fc2_b  = (const float*)d_in[12];
  float* out = (float*)d_out;

  char* ws = (char*)d_ws;
  size_t o = 0;
  auto alloc = [&](size_t bytes) { char* p = ws + o; o += bytes; return p; };
  u16* wqkv_t  = (u16*)alloc((size_t)C3 * Cc * 2);
  u16* wproj_t = (u16*)alloc((size_t)Cc * Cc * 2);
  u16* wfc1_t  = (u16*)alloc((size_t)4096 * Cc * 2);
  u16* wfc2_t  = (u16*)alloc((size_t)Cc * 4096 * 2);
  u16* h_bf    = (u16*)alloc((size_t)ROWS * Cc * 2);
  u16* y_bf    = (u16*)alloc((size_t)ROWS * Cc * 2);
  u16* qkv_raw = (u16*)alloc((size_t)ROWS * C3 * 2);
  u16* vt      = (u16*)alloc((size_t)Bb * Hh * Dd * Tt * 2);
  u16* hh      = qkv_raw; // aliases qkv_raw+vt, both dead by FC1 time

  wcast_t<<<dim3(C3 / 32, Cc / 32), 256, 0, stream>>>(attn_w, wqkv_t, Cc, C3);
  wcast_t<<<dim3(Cc / 32, Cc / 32), 256, 0, stream>>>(proj_w, wproj_t, Cc, Cc);
  wcast_t<<<dim3(4096 / 32, Cc / 32), 256, 0, stream>>>(fc1_w, wfc1_t, Cc, 4096);
  wcast_t<<<dim3(Cc / 32, 4096 / 32), 256, 0, stream>>>(fc2_w, wfc2_t, 4096, Cc);

  ln_kernel<<<ROWS, 256, 0, stream>>>(x, ln1_g, ln1_b, h_bf);
  gemm256<EPI_BIAS_BF16><<<32 * (C3 / 256), 512, 0, stream>>>(
      h_bf, wqkv_t, attn_b, nullptr, qkv_raw, ROWS, C3, Cc);
  build_vt<<<dim3(Tt / 64, Hh, Bb), 256, 0, stream>>>(qkv_raw, vt);
  flash_attn<<<dim3(512), 256, 0, stream>>>(qkv_raw, vt, y_bf);
  gemm256<EPI_BIAS_RES_F32><<<32 * (Cc / 256), 512, 0, stream>>>(
      y_bf, wproj_t, proj_b, x, out, ROWS, Cc, Cc);
  ln_kernel<<<ROWS, 256, 0, stream>>>(out, ln2_g, ln2_b, h_bf);
  gemm256<EPI_BIAS_RELU_BF16><<<32 * (4096 / 256), 512, 0, stream>>>(
      h_bf, wfc1_t, fc1_b, nullptr, hh, ROWS, 4096, Cc);
  gemm256<EPI_BIAS_RES_F32><<<32 * (Cc / 256), 512, 0, stream>>>(
      hh, wfc2_t, fc2_b, out, out, ROWS, Cc, 4096);
}

// Round 7
// 447.757 us; speedup vs baseline: 1.1566x; 1.1566x over previous
//
#include <hip/hip_runtime.h>
#include <cstdint>
#include <cstddef>

typedef __bf16 bf16x8 __attribute__((ext_vector_type(8)));
typedef float f32x4 __attribute__((ext_vector_type(4)));
typedef float f32x16 __attribute__((ext_vector_type(16)));
typedef unsigned short u16;
typedef unsigned uint2v __attribute__((ext_vector_type(2)));

namespace {
constexpr int Bb = 4, Tt = 2048, Cc = 1024, Hh = 16, Dd = 64;
constexpr int ROWS = Bb * Tt;   // 8192
constexpr int C3 = 3 * Cc;      // 3072
constexpr float LNEPS = 1e-5f;
constexpr float SCL2 = 0.18033688011112042f; // 0.125 * log2(e)
}

__device__ __forceinline__ u16 f2bf(float f) {
  union { float f; unsigned u; } v; v.f = f;
  return (u16)((v.u + 0x7fffu + ((v.u >> 16) & 1u)) >> 16);
}
__device__ __forceinline__ u16 bfn(float f) {
  union { __bf16 b; u16 u; } t; t.b = (__bf16)f; return t.u;
}
__device__ __forceinline__ unsigned pk2(float lo, float hi) {
  union { __bf16 b[2]; unsigned u; } t;
  t.b[0] = (__bf16)lo; t.b[1] = (__bf16)hi;
  return t.u;
}
__device__ __forceinline__ float exp2_hw(float x) {
  float r;
  asm("v_exp_f32 %0, %1" : "=v"(r) : "v"(x));
  return r;
}
// lane[i] <-> lane[i+32] exchange on the VALU (not the LDS pipe).
// ret[0] = {a.lo, b.lo}(per-lane: l<32 ? a[l] : b[l-32]);
// ret[1] = {a.hi, b.hi}(per-lane: l<32 ? a[l+32] : b[l]).
__device__ __forceinline__ uint2v plswap(unsigned a, unsigned b) {
  return __builtin_amdgcn_permlane32_swap(a, b, false, false);
}
__device__ __forceinline__ float xhalf_max(float x) {
  union { float f; unsigned u; } c; c.f = x;
  uint2v r = plswap(c.u, c.u);
  union { unsigned u; float f; } a, b; a.u = r[0]; b.u = r[1];
  return fmaxf(a.f, b.f);
}
__device__ __forceinline__ float xhalf_sum(float x) {
  union { float f; unsigned u; } c; c.f = x;
  uint2v r = plswap(c.u, c.u);
  union { unsigned u; float f; } a, b; a.u = r[0]; b.u = r[1];
  return a.f + b.f;
}

typedef __attribute__((address_space(3))) unsigned lds_u32;
typedef __attribute__((address_space(1))) const unsigned glb_u32;
__device__ __forceinline__ void gload_lds16(const u16* g, u16* l) {
  __builtin_amdgcn_global_load_lds((glb_u32*)g, (lds_u32*)l, 16, 0, 0);
}

// ---------------- LayerNorm (fp32 in -> bf16 out) ----------------
__global__ __launch_bounds__(256) void ln_kernel(
    const float* __restrict__ x, const float* __restrict__ g,
    const float* __restrict__ b, u16* __restrict__ out)
{
  const int row = blockIdx.x;
  const int tid = threadIdx.x;
  const float4 v = reinterpret_cast<const float4*>(x + (size_t)row * Cc)[tid];
  float s  = v.x + v.y + v.z + v.w;
  float ss = v.x * v.x + v.y * v.y + v.z * v.z + v.w * v.w;
#pragma unroll
  for (int off = 32; off; off >>= 1) {
    s  += __shfl_xor(s, off);
    ss += __shfl_xor(ss, off);
  }
  __shared__ float sa[4], sb[4];
  const int w = tid >> 6;
  if ((tid & 63) == 0) { sa[w] = s; sb[w] = ss; }
  __syncthreads();
  s  = sa[0] + sa[1] + sa[2] + sa[3];
  ss = sb[0] + sb[1] + sb[2] + sb[3];
  const float mu   = s * (1.0f / Cc);
  const float var  = ss * (1.0f / Cc) - mu * mu;
  const float rstd = rsqrtf(var + LNEPS);
  const float4 gv = reinterpret_cast<const float4*>(g)[tid];
  const float4 bv = reinterpret_cast<const float4*>(b)[tid];
  ushort4 o;
  o.x = f2bf((v.x - mu) * rstd * gv.x + bv.x);
  o.y = f2bf((v.y - mu) * rstd * gv.y + bv.y);
  o.z = f2bf((v.z - mu) * rstd * gv.z + bv.z);
  o.w = f2bf((v.w - mu) * rstd * gv.w + bv.w);
  reinterpret_cast<ushort4*>(out + (size_t)row * Cc)[tid] = o;
}

// ---------------- weight transpose + cast: w[K][N] f32 -> wt[N][K] bf16 ----------------
__global__ __launch_bounds__(256) void wcast_t(
    const float* __restrict__ w, u16* __restrict__ wt, int K, int N)
{
  __shared__ float tile[32][33];
  const int n0 = blockIdx.x * 32, k0 = blockIdx.y * 32;
  const int tx = threadIdx.x & 31, ty = threadIdx.x >> 5; // 32x8
#pragma unroll
  for (int i = 0; i < 4; i++)
    tile[ty + i * 8][tx] = w[(size_t)(k0 + ty + i * 8) * N + n0 + tx];
  __syncthreads();
#pragma unroll
  for (int i = 0; i < 4; i++)
    wt[(size_t)(n0 + ty + i * 8) * K + k0 + tx] = f2bf(tile[tx][ty + i * 8]);
}

enum { EPI_BIAS_BF16 = 0, EPI_BIAS_RELU_BF16 = 1, EPI_BIAS_RES_F32 = 2 };

// ---------------- GEMM 256x256, 4-slot ring, counted vmcnt (T1..T5) ----------------
// BK=32; ring of 4 K-tile slots (A,B each 4x16KB = 128KB LDS). Tile kt: 2 phases
// x 16 MFMA. While computing tile kt, stage tile kt+3 into slot (kt+3)&3 (last
// read at tile kt-1 -> WAR safe: writes issued after the barrier that ends the
// reads). vmcnt(8) once per tile (4/0 only at the tail). Swizzle: 16B-chunk
// ^= (row>>1)&3 on BOTH global source and ds_read (2-way residual = free).
template <int EPI>
__global__ __launch_bounds__(512, 2) void gemm256(
    const u16* __restrict__ A, const u16* __restrict__ Bt,
    const float* __restrict__ bias, const float* __restrict__ res,
    void* __restrict__ outp, int M, int N, int K)
{
  __shared__ alignas(16) u16 Al[4][256 * 32];
  __shared__ alignas(16) u16 Bl[4][256 * 32];

  const int tid  = threadIdx.x;
  const int lane = tid & 63;
  const int wv   = tid >> 6;            // 8 waves: 2M x 4N
  const int wr   = wv >> 2, wc = wv & 3;
  const int lr   = lane & 15;
  const int lg   = (lane >> 4) & 3;

  // T1: XCD-bijective swizzle (grid % 8 == 0 by construction)
  const int q8  = (int)gridDim.x >> 3;
  const int lid = ((int)blockIdx.x & 7) * q8 + ((int)blockIdx.x >> 3);
  const int bm = (lid & 31) << 8;       // M/256 == 32 fixed
  const int bn = (lid >> 5) << 8;

  // staging: pass P covers row P*128 + (tid>>2), dest chunk tid&3,
  // source chunk inverse-swizzled.
  const int srl  = tid >> 2;                       // 0..127
  const int schk = (tid & 3) ^ ((tid >> 3) & 3);
  const u16* gA = A  + (size_t)(bm + srl) * K + schk * 8;
  const u16* gB = Bt + (size_t)(bn + srl) * K + schk * 8;
  const size_t rowK128 = (size_t)128 * K;

  // frag reads: row stride 32 u16 (64B); swizzled chunk = lg ^ ((lr>>1)&3)
  const int fsw  = (lg ^ ((lr >> 1) & 3)) * 8;
  const int arow = wr * 128 + lr;       // + mi*16
  const int brow = wc * 64 + lr;        // + nj*16

  f32x4 acc[8][4];
#pragma unroll
  for (int mi = 0; mi < 8; mi++)
#pragma unroll
    for (int nj = 0; nj < 4; nj++)
      acc[mi][nj] = (f32x4){0.f, 0.f, 0.f, 0.f};

  const int NT = K >> 5;   // BK=32 tiles (K=1024 -> 32, K=4096 -> 128)

  auto stageA = [&](int t) {
    u16* d = &Al[t & 3][tid * 8];
    gload_lds16(gA + (size_t)t * 32, d);
    gload_lds16(gA + rowK128 + (size_t)t * 32, d + 4096);
  };
  auto stageB = [&](int t) {
    u16* d = &Bl[t & 3][tid * 8];
    gload_lds16(gB + (size_t)t * 32, d);
    gload_lds16(gB + rowK128 + (size_t)t * 32, d + 4096);
  };

  // prologue: 3 tiles in flight, wait for tile 0 only (counted)
  for (int t = 0; t < 3; ++t) { stageA(t); stageB(t); }
  asm volatile("s_waitcnt vmcnt(8)" ::: "memory");
  asm volatile("s_barrier" ::: "memory");

  for (int kt = 0; kt < NT; ++kt) {
    const u16* Ab = &Al[kt & 3][0];
    const u16* Bb = &Bl[kt & 3][0];
    const bool st = (kt + 3 < NT);

    // ---- phase 0: B-frags (kept across both phases) + A mi 0-3 ----
    bf16x8 bf[4];
#pragma unroll
    for (int nj = 0; nj < 4; ++nj)
      bf[nj] = *reinterpret_cast<const bf16x8*>(Bb + (brow + nj * 16) * 32 + fsw);
    bf16x8 af[4];
#pragma unroll
    for (int m = 0; m < 4; ++m)
      af[m] = *reinterpret_cast<const bf16x8*>(Ab + (arow + m * 16) * 32 + fsw);
    if (st) stageA(kt + 3);
    asm volatile("s_barrier" ::: "memory");
    __builtin_amdgcn_s_setprio(1);
#pragma unroll
    for (int m = 0; m < 4; ++m)
#pragma unroll
      for (int nj = 0; nj < 4; ++nj)
        acc[m][nj] = __builtin_amdgcn_mfma_f32_16x16x32_bf16(af[m], bf[nj], acc[m][nj], 0, 0, 0);
    __builtin_amdgcn_s_setprio(0);
    asm volatile("s_barrier" ::: "memory");

    // ---- phase 1: A mi 4-7 ----
#pragma unroll
    for (int m = 0; m < 4; ++m)
      af[m] = *reinterpret_cast<const bf16x8*>(Ab + (arow + (m + 4) * 16) * 32 + fsw);
    if (st) stageB(kt + 3);
    if (kt < NT - 3)       { asm volatile("s_waitcnt vmcnt(8)" ::: "memory"); }
    else if (kt == NT - 3) { asm volatile("s_waitcnt vmcnt(4)" ::: "memory"); }
    else if (kt == NT - 2) { asm volatile("s_waitcnt vmcnt(0)" ::: "memory"); }
    asm volatile("s_barrier" ::: "memory");
    __builtin_amdgcn_s_setprio(1);
#pragma unroll
    for (int m = 0; m < 4; ++m)
#pragma unroll
      for (int nj = 0; nj < 4; ++nj)
        acc[m + 4][nj] = __builtin_amdgcn_mfma_f32_16x16x32_bf16(af[m], bf[nj], acc[m + 4][nj], 0, 0, 0);
    __builtin_amdgcn_s_setprio(0);
    asm volatile("s_barrier" ::: "memory");
  }

  // epilogue
#pragma unroll
  for (int mi = 0; mi < 8; ++mi) {
    const int row0 = bm + wr * 128 + mi * 16 + lg * 4;
#pragma unroll
    for (int nj = 0; nj < 4; ++nj) {
      const int col = bn + wc * 64 + nj * 16 + lr;
      const float bv = bias[col];
#pragma unroll
      for (int r = 0; r < 4; ++r) {
        const int row = row0 + r;
        float v = acc[mi][nj][r] + bv;
        if constexpr (EPI == EPI_BIAS_RELU_BF16) v = fmaxf(v, 0.0f);
        if constexpr (EPI == EPI_BIAS_RES_F32) {
          float* out = (float*)outp;
          out[(size_t)row * N + col] = v + res[(size_t)row * N + col];
        } else {
          ((u16*)outp)[(size_t)row * N + col] = f2bf(v);
        }
      }
    }
  }
}

// ---------------- GEMM 128x128 (m97 structure, proven) for proj/FC2 ----------------
template <int EPI>
__global__ __launch_bounds__(256, 3) void gemm_bt(
    const u16* __restrict__ A, const u16* __restrict__ Bt,
    const float* __restrict__ bias, const float* __restrict__ res,
    void* __restrict__ outp, int M, int N, int K)
{
  constexpr int BM = 128, BN = 128, BK = 64;
  __shared__ alignas(16) u16 As[BM][BK];
  __shared__ alignas(16) u16 Bs[BN][BK];
  const int tid  = threadIdx.x;
  const int lane = tid & 63;
  const int wv   = tid >> 6;
  const int wr   = wv >> 1, wc = wv & 1;
  const int lr   = lane & 15, lg = lane >> 4;

  const int q8  = (int)gridDim.x >> 3;
  const int lid = ((int)blockIdx.x & 7) * q8 + ((int)blockIdx.x >> 3);
  const int bm = (lid & 63) << 7;     // M/128 == 64, bm-fastest
  const int bn = (lid >> 6) << 7;

  f32x4 acc[4][4];
#pragma unroll
  for (int mi = 0; mi < 4; mi++)
#pragma unroll
    for (int nj = 0; nj < 4; nj++)
      acc[mi][nj] = (f32x4){0.f, 0.f, 0.f, 0.f};

  const int srow = tid >> 3;
  const int scol = (tid & 7) * 8;
  const u16* ga = &A [(size_t)(bm + srow) * K + scol];
  const u16* gb = &Bt[(size_t)(bn + srow) * K + scol];
  u16* as_dst = &As[0][0] + (size_t)tid * 8;
  u16* bs_dst = &Bs[0][0] + (size_t)tid * 8;

  for (int k0 = 0; k0 < K; k0 += BK) {
#pragma unroll
    for (int p = 0; p < 4; p++) {
      gload_lds16(ga + (size_t)p * 32 * K + k0, as_dst + p * 2048);
      gload_lds16(gb + (size_t)p * 32 * K + k0, bs_dst + p * 2048);
    }
    __syncthreads();
#pragma unroll
    for (int kk = 0; kk < BK; kk += 32) {
      bf16x8 af[4], bfr[4];
#pragma unroll
      for (int mi = 0; mi < 4; mi++)
        af[mi] = *reinterpret_cast<const bf16x8*>(&As[wr * 64 + mi * 16 + lr][kk + lg * 8]);
#pragma unroll
      for (int nj = 0; nj < 4; nj++)
        bfr[nj] = *reinterpret_cast<const bf16x8*>(&Bs[wc * 64 + nj * 16 + lr][kk + lg * 8]);
#pragma unroll
      for (int mi = 0; mi < 4; mi++)
#pragma unroll
        for (int nj = 0; nj < 4; nj++)
          acc[mi][nj] = __builtin_amdgcn_mfma_f32_16x16x32_bf16(af[mi], bfr[nj], acc[mi][nj], 0, 0, 0);
    }
    __syncthreads();
  }

#pragma unroll
  for (int mi = 0; mi < 4; mi++) {
#pragma unroll
    for (int nj = 0; nj < 4; nj++) {
      const int col = bn + wc * 64 + nj * 16 + lr;
      const float bv = bias[col];
#pragma unroll
      for (int r = 0; r < 4; r++) {
        const int row = bm + wr * 64 + mi * 16 + lg * 4 + r;
        float v = acc[mi][nj][r] + bv;
        if constexpr (EPI == EPI_BIAS_RELU_BF16) v = fmaxf(v, 0.0f);
        if constexpr (EPI == EPI_BIAS_RES_F32) {
          float* out = (float*)outp;
          out[(size_t)row * N + col] = v + res[(size_t)row * N + col];
        } else {
          ((u16*)outp)[(size_t)row * N + col] = f2bf(v);
        }
      }
    }
  }
}

// ---------------- V transpose: qkv[B][T][3C] (v part) -> vt[B][H][D][T] ----------------
__global__ __launch_bounds__(256) void build_vt(
    const u16* __restrict__ qkv, u16* __restrict__ vt)
{
  __shared__ u16 tile[64][80];
  const int t0 = blockIdx.x * 64;
  const int h  = blockIdx.y;
  const int b  = blockIdx.z;
  const int tid = threadIdx.x;
  const int rr = tid >> 3, cc = (tid & 7) * 8;
#pragma unroll
  for (int p = 0; p < 2; p++) {
    const int t = rr + p * 32;
    bf16x8 v = *reinterpret_cast<const bf16x8*>(
        &qkv[(size_t)(b * Tt + t0 + t) * C3 + 2 * Cc + h * Dd + cc]);
    *reinterpret_cast<bf16x8*>(&tile[t][cc]) = v;
  }
  __syncthreads();
#pragma unroll
  for (int p = 0; p < 2; p++) {
    const int d = rr + p * 32;
    union { u16 u[8]; int4 v; } o;
#pragma unroll
    for (int j = 0; j < 8; j++) o.u[j] = tile[cc + j][d];
    *reinterpret_cast<int4*>(&vt[(size_t)((b * Hh + h) * Dd + d) * Tt + t0 + cc]) = o.v;
  }
}

// ---------------- flash attention: R4 structure, shfl -> permlane32_swap ----------------
__global__ __launch_bounds__(256, 4) void flash_attn(
    const u16* __restrict__ qkv,   // [B][T][3C]
    const u16* __restrict__ vt,    // [B][H][D][T]
    u16* __restrict__ y)           // [B][T][C]
{
  const int tid = threadIdx.x, lane = tid & 63, wv = tid >> 6;
  const int l31 = lane & 31, hf = lane >> 5;

  // 512 blocks = 8 XCDs x 64; lid = bh*8 + pg (bh pinned to one XCD)
  const int bid = blockIdx.x;
  const int lid = (bid & 7) * 64 + (bid >> 3);
  const int bh = lid >> 3, pg = lid & 7;
  const int b = bh >> 4, h = bh & 15;
  const int pi = pg * 4 + wv;        // 0..31 -> tiles {pi, 63-pi}

  const u16* qbase = qkv + (size_t)b * Tt * C3 + h * Dd;
  const u16* kbase = qbase + Cc;
  const u16* vbase = vt + (size_t)bh * Dd * Tt;

#pragma unroll
  for (int ti = 0; ti < 2; ti++) {
    const int t = ti ? (63 - pi) : pi;
    const int q0 = t * 32;

    bf16x8 qf[4];
#pragma unroll
    for (int kc = 0; kc < 4; kc++)
      qf[kc] = *reinterpret_cast<const bf16x8*>(
          &qbase[(size_t)(q0 + l31) * C3 + kc * 16 + hf * 8]);

    f32x16 oacc[2];
#pragma unroll
    for (int i = 0; i < 16; i++) { oacc[0][i] = 0.f; oacc[1][i] = 0.f; }
    float mrun = -INFINITY, lpart = 0.0f;

    const u16* kptr = &kbase[(size_t)l31 * C3 + hf * 8];
    const u16* vptr0 = &vbase[(size_t)l31 * Tt + hf * 8];
    const u16* vptr1 = vptr0 + (size_t)32 * Tt;
    bf16x8 kf[4];
#pragma unroll
    for (int kc = 0; kc < 4; kc++)
      kf[kc] = *reinterpret_cast<const bf16x8*>(kptr + kc * 16);

    for (int k0 = 0; k0 <= q0; k0 += 32) {
      bf16x8 vf[2][2];
#pragma unroll
      for (int ch = 0; ch < 2; ch++) {
        vf[0][ch] = *reinterpret_cast<const bf16x8*>(vptr0 + ch * 16);
        vf[1][ch] = *reinterpret_cast<const bf16x8*>(vptr1 + ch * 16);
      }
      vptr0 += 32; vptr1 += 32;

      f32x16 sacc;
#pragma unroll
      for (int i = 0; i < 16; i++) sacc[i] = 0.f;
#pragma unroll
      for (int kc = 0; kc < 4; kc++)
        sacc = __builtin_amdgcn_mfma_f32_32x32x16_bf16(kf[kc], qf[kc], sacc, 0, 0, 0);

      kptr += (size_t)32 * C3;
      bf16x8 kn[4];
      if (k0 < q0) {
#pragma unroll
        for (int kc = 0; kc < 4; kc++)
          kn[kc] = *reinterpret_cast<const bf16x8*>(kptr + kc * 16);
      }

      float sv[16];
#pragma unroll
      for (int r = 0; r < 16; r++) sv[r] = sacc[r];
      if (k0 == q0) {   // diagonal: mask key > q (key = (r&3)+8*(r>>2)+4hf)
#pragma unroll
        for (int r = 0; r < 16; r++)
          if ((r & 3) + 8 * (r >> 2) + 4 * hf > l31) sv[r] = -INFINITY;
      }

      float ma = fmaxf(fmaxf(sv[0], sv[1]), fmaxf(sv[2], sv[3]));
      float mb = fmaxf(fmaxf(sv[4], sv[5]), fmaxf(sv[6], sv[7]));
      float mc = fmaxf(fmaxf(sv[8], sv[9]), fmaxf(sv[10], sv[11]));
      float md = fmaxf(fmaxf(sv[12], sv[13]), fmaxf(sv[14], sv[15]));
      float m8 = fmaxf(fmaxf(ma, mb), fmaxf(mc, md));
      m8 = xhalf_max(m8);   // was shfl_xor(32)

      if (!__all(m8 - mrun <= 64.0f)) {   // defer-max: 64 raw = 8 nats
        const float mnew  = fmaxf(mrun, m8);
        const float alpha = exp2_hw((mrun - mnew) * SCL2);
        lpart *= alpha;
#pragma unroll
        for (int i = 0; i < 16; i++) { oacc[0][i] *= alpha; oacc[1][i] *= alpha; }
        mrun = mnew;
      }

      const float ms = mrun * SCL2;
      float p[16];
#pragma unroll
      for (int r = 0; r < 16; r++)
        p[r] = exp2_hw(fmaf(sv[r], SCL2, -ms));
      {
        float s0 = (p[0] + p[1]) + (p[2] + p[3]);
        float s1 = (p[4] + p[5]) + (p[6] + p[7]);
        float s2 = (p[8] + p[9]) + (p[10] + p[11]);
        float s3 = (p[12] + p[13]) + (p[14] + p[15]);
        lpart += (s0 + s1) + (s2 + s3);
      }

      // P^T B-frags via permlane32_swap (VALU) instead of 8 ds_bpermute
      unsigned pw[2][4];
#pragma unroll
      for (int ch = 0; ch < 2; ch++) {
        const int bs = ch * 8;
        unsigned w0 = pk2(p[bs + 0], p[bs + 1]);
        unsigned w1 = pk2(p[bs + 2], p[bs + 3]);
        unsigned w2 = pk2(p[bs + 4], p[bs + 5]);
        unsigned w3 = pk2(p[bs + 6], p[bs + 7]);
        uint2v r02 = plswap(w0, w2);
        uint2v r13 = plswap(w1, w3);
        pw[ch][0] = r02[0]; pw[ch][2] = r02[1];
        pw[ch][1] = r13[0]; pw[ch][3] = r13[1];
      }

#pragma unroll
      for (int d0i = 0; d0i < 2; d0i++)
#pragma unroll
        for (int ch = 0; ch < 2; ch++) {
          union { unsigned w[4]; bf16x8 v; } pb;
          pb.w[0] = pw[ch][0]; pb.w[1] = pw[ch][1];
          pb.w[2] = pw[ch][2]; pb.w[3] = pw[ch][3];
          oacc[d0i] = __builtin_amdgcn_mfma_f32_32x32x16_bf16(vf[d0i][ch], pb.v, oacc[d0i], 0, 0, 0);
        }

      if (k0 < q0) {
#pragma unroll
        for (int kc = 0; kc < 4; kc++) kf[kc] = kn[kc];
      }
    }

    const float ls = xhalf_sum(lpart);   // was lpart + shfl_xor(lpart,32)
    const float inv = 1.0f / ls;
    u16* yrow = y + (size_t)(b * Tt + q0 + l31) * Cc + h * Dd;
#pragma unroll
    for (int d0i = 0; d0i < 2; d0i++)
#pragma unroll
      for (int qd = 0; qd < 4; qd++) {
        ushort4 o;
        o.x = bfn(oacc[d0i][qd * 4 + 0] * inv);
        o.y = bfn(oacc[d0i][qd * 4 + 1] * inv);
        o.z = bfn(oacc[d0i][qd * 4 + 2] * inv);
        o.w = bfn(oacc[d0i][qd * 4 + 3] * inv);
        *reinterpret_cast<ushort4*>(&yrow[d0i * 32 + qd * 8 + hf * 4]) = o;
      }
  }
}

// ---------------- launch ----------------
extern "C" void kernel_launch(void* const* d_in, const int* in_sizes, int n_in,
                              void* d_out, int out_size, void* d_ws, size_t ws_size,
                              hipStream_t stream)
{
  const float* x      = (const float*)d_in[0];
  const float* ln1_g  = (const float*)d_in[1];
  const float* ln1_b  = (const float*)d_in[2];
  const float* attn_w = (const float*)d_in[3];
  const float* attn_b = (const float*)d_in[4];
  const float* proj_w = (const float*)d_in[5];
  const float* proj_b = (const float*)d_in[6];
  const float* ln2_g  = (const float*)d_in[7];
  const float* ln2_b  = (const float*)d_in[8];
  const float* fc1_w  = (const float*)d_in[9];
  const float* fc1_b  = (const float*)d_in[10];
  const float* fc2_w  = (const float*)d_in[11];
  const float* fc2_b  = (const float*)d_in[12];
  float* out = (float*)d_out;

  char* ws = (char*)d_ws;
  size_t o = 0;
  auto alloc = [&](size_t bytes) { char* p = ws + o; o += bytes; return p; };
  u16* wqkv_t  = (u16*)alloc((size_t)C3 * Cc * 2);
  u16* wproj_t = (u16*)alloc((size_t)Cc * Cc * 2);
  u16* wfc1_t  = (u16*)alloc((size_t)4096 * Cc * 2);
  u16* wfc2_t  = (u16*)alloc((size_t)Cc * 4096 * 2);
  u16* h_bf    = (u16*)alloc((size_t)ROWS * Cc * 2);
  u16* y_bf    = (u16*)alloc((size_t)ROWS * Cc * 2);
  u16* qkv_raw = (u16*)alloc((size_t)ROWS * C3 * 2);
  u16* vt      = (u16*)alloc((size_t)Bb * Hh * Dd * Tt * 2);
  u16* hh      = qkv_raw; // aliases qkv_raw+vt, both dead by FC1 time

  wcast_t<<<dim3(C3 / 32, Cc / 32), 256, 0, stream>>>(attn_w, wqkv_t, Cc, C3);
  wcast_t<<<dim3(Cc / 32, Cc / 32), 256, 0, stream>>>(proj_w, wproj_t, Cc, Cc);
  wcast_t<<<dim3(4096 / 32, Cc / 32), 256, 0, stream>>>(fc1_w, wfc1_t, Cc, 4096);
  wcast_t<<<dim3(Cc / 32, 4096 / 32), 256, 0, stream>>>(fc2_w, wfc2_t, 4096, Cc);

  ln_kernel<<<ROWS, 256, 0, stream>>>(x, ln1_g, ln1_b, h_bf);
  gemm256<EPI_BIAS_BF16><<<32 * (C3 / 256), 512, 0, stream>>>(
      h_bf, wqkv_t, attn_b, nullptr, qkv_raw, ROWS, C3, Cc);
  build_vt<<<dim3(Tt / 64, Hh, Bb), 256, 0, stream>>>(qkv_raw, vt);
  flash_attn<<<dim3(512), 256, 0, stream>>>(qkv_raw, vt, y_bf);
  gemm_bt<EPI_BIAS_RES_F32><<<64 * (Cc / 128), 256, 0, stream>>>(
      y_bf, wproj_t, proj_b, x, out, ROWS, Cc, Cc);
  ln_kernel<<<ROWS, 256, 0, stream>>>(out, ln2_g, ln2_b, h_bf);
  gemm256<EPI_BIAS_RELU_BF16><<<32 * (4096 / 256), 512, 0, stream>>>(
      h_bf, wfc1_t, fc1_b, nullptr, hh, ROWS, 4096, Cc);
  gemm_bt<EPI_BIAS_RES_F32><<<64 * (Cc / 128), 256, 0, stream>>>(
      hh, wfc2_t, fc2_b, out, out, ROWS, Cc, 4096);
}